// Round 4
// baseline (117.652 us; speedup 1.0000x reference)
//
#include <hip/hip_runtime.h>
#include <math.h>

// Canny, round 4: wave-rolling stencil, 2 columns per lane (float2).
// B=16, C=3, H=W=512 fixed. No LDS, no __syncthreads.
//
// Each wave owns a 112-col output strip (lane = column PAIR, 4 halo lanes
// each side) and streams SH=16 rows down:
//   - vertical 5-tap gauss: rolling 5-row float2 window/channel, one 8B
//     coalesced row load per channel per step, prefetched 1 iter ahead
//   - horizontal gauss + sobel horiz combos: __shfl of pair components
//   - per-channel |g|^2 argmax per element (strict > = first-max)
//   - angle bucket via sign-folded multiplicative compares (no fp div)
//   - NMS on rolling 3-row mag pairs, sigmoid via v_rcp, float2 store.

#define HDIM 512
#define WDIM 512
#define SH   16
#define NSTR (HDIM / SH)   // 32 strips
#define NGRP 5             // 5 x 112 = 560 >= 512
#define GW   112

__device__ __forceinline__ float shfl1(float v, int src) {
    return __shfl(v, src, 64);
}

__global__ __launch_bounds__(256) void canny_wave2(
    const float* __restrict__ x, const int* __restrict__ lt,
    float* __restrict__ out)
{
    const int lane = threadIdx.x & 63;
    const int wid  = blockIdx.x * 4 + (threadIdx.x >> 6);
    const int b    = wid / (NGRP * NSTR);
    const int rem  = wid - b * (NGRP * NSTR);
    const int g    = rem / NSTR;
    const int s    = rem - g * NSTR;
    const int R0   = s * SH;
    const int c0   = g * GW + 2 * lane - 8;   // pair base col (even)
    const int c1   = c0 + 1;
    const bool colok = (unsigned)c0 < (unsigned)WDIM;  // pairs never straddle
    const float t  = (float)lt[0];

    const float w0 = 0.05448868454964294f;   // gauss5(sigma=1)/sum
    const float w1 = 0.24420134200323332f;
    const float w2 = 0.4026199468942475f;
    const float T1c = 0.41421356237309503f;  // tan(pi/8)
    const float T3c = 2.414213562373095f;    // tan(3pi/8)

    const float* xb0 = x + (size_t)(b * 3) * (HDIM * WDIM);

    auto ld2 = [&](int c, int ri) -> float2 {
        if (colok && (unsigned)ri < (unsigned)HDIM)
            return *(const float2*)(xb0 + (size_t)c * (HDIM * WDIM)
                                        + (size_t)ri * WDIM + c0);
        return make_float2(0.f, 0.f);
    };
    // horizontal 5-tap blur on a column pair
    auto hb2 = [&](float2 v) -> float2 {
        float lx = shfl1(v.x, lane - 1), ly = shfl1(v.y, lane - 1);
        float rx = shfl1(v.x, lane + 1), ry = shfl1(v.y, lane + 1);
        float2 r;
        r.x = w0 * (lx + rx) + w1 * (ly + v.y) + w2 * v.x;
        r.y = w0 * (ly + ry) + w1 * (v.x + rx) + w2 * v.y;
        return r;
    };
    auto dirof = [&](float gx, float gy) -> int {
        const float gys = (gy == 0.f) ? 1e-9f : gy;
        const float sg  = (gys > 0.f) ? 1.f : -1.f;
        const float gxs = gx * sg;            // a>=c  <=>  gxs >= c*|gys|
        const float gya = fabsf(gys);
        const float a3 = T3c * gya, a1 = T1c * gya;
        return (gxs >= a3 || gxs < -a3) ? 2
             : (gxs >= a1) ? 1
             : (gxs >= -a1) ? 0 : 3;
    };

    // rolling state
    float2 xa[3], xbw[3], xcw[3], xdw[3];  // x rows m-1..m+2
    float2 blm[3], bl0[3];                 // blurred rows m-1, m
    float2 xnext[3];                       // prefetched x row (m+3 at loop top)
    float2 mg0, mg1, mg2;                  // mag rows m-3, m-2, m-1 (post-roll)
    int d1x = 0, d1y = 0, d2x = 0, d2y = 0;
    mg0 = mg1 = mg2 = make_float2(0.f, 0.f);

    // ---- prologue: bl rows R0-2, R0-1; x window R0-2..R0+1; prefetch R0+2
    #pragma unroll
    for (int c = 0; c < 3; ++c) {
        float2 t0 = ld2(c, R0 - 4), t1 = ld2(c, R0 - 3), t2 = ld2(c, R0 - 2);
        float2 t3 = ld2(c, R0 - 1), t4 = ld2(c, R0),     t5 = ld2(c, R0 + 1);
        float2 vA, vB;
        vA.x = w0 * (t0.x + t4.x) + w1 * (t1.x + t3.x) + w2 * t2.x;
        vA.y = w0 * (t0.y + t4.y) + w1 * (t1.y + t3.y) + w2 * t2.y;
        vB.x = w0 * (t1.x + t5.x) + w1 * (t2.x + t4.x) + w2 * t3.x;
        vB.y = w0 * (t1.y + t5.y) + w1 * (t2.y + t4.y) + w2 * t3.y;
        blm[c] = hb2(vA);
        bl0[c] = hb2(vB);
        xa[c] = t2; xbw[c] = t3; xcw[c] = t4; xdw[c] = t5;
        xnext[c] = ld2(c, R0 + 2);
    }

    auto nms_store = [&](int row) {
        float m0l = shfl1(mg0.y, lane - 1), m0r = shfl1(mg0.x, lane + 1);
        float m1l = shfl1(mg1.y, lane - 1), m1r = shfl1(mg1.x, lane + 1);
        float m2l = shfl1(mg2.y, lane - 1), m2r = shfl1(mg2.x, lane + 1);
        // element .x (col c0): left neighbor = m*l, right = own .y
        float n1x = (d1x == 0) ? mg0.x : (d1x == 1) ? m0l
                  : (d1x == 2) ? m1l   : mg0.y;
        float n2x = (d1x == 0) ? mg2.x : (d1x == 1) ? mg2.y
                  : (d1x == 2) ? mg1.y : m2l;
        // element .y (col c1): left = own .x, right = m*r
        float n1y = (d1y == 0) ? mg0.y : (d1y == 1) ? mg0.x
                  : (d1y == 2) ? mg1.x : m0r;
        float n2y = (d1y == 0) ? mg2.y : (d1y == 1) ? m2r
                  : (d1y == 2) ? m1r   : mg2.x;
        float sx = (mg1.x >= n1x && mg1.x >= n2x) ? mg1.x : 0.f;
        float sy = (mg1.y >= n1y && mg1.y >= n2y) ? mg1.y : 0.f;
        float vx = (sx >= t) ? sx : 1e-9f;
        float vy = (sy >= t) ? sy : 1e-9f;
        float ox = __builtin_amdgcn_rcpf(1.f + __expf(-vx));
        float oy = __builtin_amdgcn_rcpf(1.f + __expf(-vy));
        if (colok && lane >= 4 && lane < 60)
            *(float2*)&out[((size_t)b * HDIM + row) * WDIM + c0]
                = make_float2(ox, oy);
    };

    // ---- main loop: step m computes mag[m], outputs row m-2 ----
    for (int m = R0 - 1; m <= R0 + SH; ++m) {
        float2 xn[3];
        #pragma unroll
        for (int c = 0; c < 3; ++c) xn[c] = xnext[c];
        if (m < R0 + SH) {                  // prefetch row m+4 for next iter
            #pragma unroll
            for (int c = 0; c < 3; ++c) xnext[c] = ld2(c, m + 4);
        }

        if (m >= R0 + 2) nms_store(m - 2);

        float bestx = -1.f, besty = -1.f;
        float bgxx = 0.f, bgxy = 0.f, bgyx = 0.f, bgyy = 0.f;
        #pragma unroll
        for (int c = 0; c < 3; ++c) {
            float2 vb;
            vb.x = w0 * (xa[c].x + xn[c].x) + w1 * (xbw[c].x + xdw[c].x)
                 + w2 * xcw[c].x;
            vb.y = w0 * (xa[c].y + xn[c].y) + w1 * (xbw[c].y + xdw[c].y)
                 + w2 * xcw[c].y;
            float2 blp = hb2(vb);                       // bl row m+1
            float2 bm = (m == 0)        ? bl0[c] : blm[c];   // row replicate
            float2 bp = (m == HDIM - 1) ? bl0[c] : blp;
            float2 tt, uu;
            tt.x = bm.x + 2.f * bl0[c].x + bp.x;
            tt.y = bm.y + 2.f * bl0[c].y + bp.y;
            uu.x = bp.x - bm.x;
            uu.y = bp.y - bm.y;
            float tly = shfl1(tt.y, lane - 1), trx = shfl1(tt.x, lane + 1);
            float uly = shfl1(uu.y, lane - 1), urx = shfl1(uu.x, lane + 1);
            float tl_x = (c0 == 0)        ? tt.x : tly;  // col replicate
            float tr_y = (c1 == WDIM - 1) ? tt.y : trx;
            float ul_x = (c0 == 0)        ? uu.x : uly;
            float ur_y = (c1 == WDIM - 1) ? uu.y : urx;
            float gx_x = 0.125f * (tt.y - tl_x);
            float gx_y = 0.125f * (tr_y - tt.x);
            float gy_x = 0.125f * (ul_x + 2.f * uu.x + uu.y);
            float gy_y = 0.125f * (uu.x + 2.f * uu.y + ur_y);
            float m2x = gx_x * gx_x + gy_x * gy_x;
            float m2y = gx_y * gx_y + gy_y * gy_y;
            if (m2x > bestx) { bestx = m2x; bgxx = gx_x; bgyx = gy_x; }
            if (m2y > besty) { besty = m2y; bgxy = gx_y; bgyy = gy_y; }
            blm[c] = bl0[c]; bl0[c] = blp;
            xa[c] = xbw[c]; xbw[c] = xcw[c]; xcw[c] = xdw[c]; xdw[c] = xn[c];
        }
        float magx = __builtin_amdgcn_sqrtf(bestx + 1e-9f);
        float magy = __builtin_amdgcn_sqrtf(besty + 1e-9f);
        const bool rowok = (unsigned)m < (unsigned)HDIM;
        if (!colok || !rowok) { magx = 0.f; magy = 0.f; }  // zero-pad
        const int dnx = dirof(bgxx, bgyx);
        const int dny = dirof(bgxy, bgyy);
        mg0 = mg1; mg1 = mg2; mg2 = make_float2(magx, magy);
        d1x = d2x; d1y = d2y; d2x = dnx; d2y = dny;
    }
    nms_store(R0 + SH - 1);   // last output row
}

extern "C" void kernel_launch(void* const* d_in, const int* in_sizes, int n_in,
                              void* d_out, int out_size, void* d_ws, size_t ws_size,
                              hipStream_t stream) {
    const float* x  = (const float*)d_in[0];
    const int*   lt = (const int*)d_in[1];
    float* out = (float*)d_out;
    // 16 batches x 5 col-groups x 32 strips = 2560 waves = 640 blocks
    const int nblocks = (16 * NGRP * NSTR) / 4;
    canny_wave2<<<nblocks, dim3(256), 0, stream>>>(x, lt, out);
}

// Round 5
// 117.068 us; speedup vs baseline: 1.0050x; 1.0050x over previous
//
#include <hip/hip_runtime.h>
#include <math.h>

// Canny, round 5: wave-rolling stencil, 2 cols/lane, packed-fp32 (v_pk_*),
// SH=8 (5120 waves for latency hiding), edge-specialized templates.
// B=16, C=3, H=W=512 fixed. No LDS, no __syncthreads.

typedef float v2f __attribute__((ext_vector_type(2)));

#define HDIM 512
#define WDIM 512
#define SH   8
#define NSTR (HDIM / SH)   // 64 strips
#define NGRP 5             // 5 x 112 = 560 >= 512
#define GW   112

__device__ __forceinline__ float shfl1(float v, int src) {
    return __shfl(v, src, 64);
}

template<bool RE, bool CE>
__device__ __forceinline__ void run(
    const float* __restrict__ xb0, float t, float* __restrict__ out,
    int b, int R0, int c0, int lane)
{
    const bool colok = !CE || ((unsigned)c0 < (unsigned)WDIM);

    const float w0 = 0.05448868454964294f;   // gauss5(sigma=1)/sum
    const float w1 = 0.24420134200323332f;
    const float w2 = 0.4026199468942475f;
    const float T1c = 0.41421356237309503f;  // tan(pi/8)
    const float T3c = 2.414213562373095f;    // tan(3pi/8)

    auto ld2 = [&](int c, int ri) -> v2f {
        if ((CE && !colok) || (RE && (unsigned)ri >= (unsigned)HDIM)) {
            v2f z = {0.f, 0.f};
            return z;
        }
        return *(const v2f*)(xb0 + (size_t)c * (HDIM * WDIM)
                                 + (size_t)ri * WDIM + c0);
    };
    // horizontal 5-tap blur on a column pair (packed)
    auto hb2 = [&](v2f v) -> v2f {
        v2f L, R;
        L.x = shfl1(v.x, lane - 1); L.y = shfl1(v.y, lane - 1);
        R.x = shfl1(v.x, lane + 1); R.y = shfl1(v.y, lane + 1);
        v2f p = {L.y, v.x};
        v2f q = {v.y, R.x};
        return w0 * (L + R) + w1 * (p + q) + w2 * v;
    };
    auto dirof = [&](float gx, float gy) -> int {
        const float gys = (gy == 0.f) ? 1e-9f : gy;
        const float sg  = (gys > 0.f) ? 1.f : -1.f;
        const float gxs = gx * sg;            // a>=c  <=>  gxs >= c*|gys|
        const float gya = fabsf(gys);
        const float a3 = T3c * gya, a1 = T1c * gya;
        return (gxs >= a3 || gxs < -a3) ? 2
             : (gxs >= a1) ? 1
             : (gxs >= -a1) ? 0 : 3;
    };

    // rolling state
    v2f xa[3], xbw[3], xcw[3], xdw[3];   // x rows m-1..m+2
    v2f blm[3], bl0[3];                  // blurred rows m-1, m
    v2f xnext[3];                        // prefetched x row
    v2f mg0 = {0.f, 0.f}, mg1 = {0.f, 0.f}, mg2 = {0.f, 0.f};
    int d1x = 0, d1y = 0, d2x = 0, d2y = 0;

    // ---- prologue: bl rows R0-2, R0-1; x window R0-2..R0+1; prefetch R0+2
    #pragma unroll
    for (int c = 0; c < 3; ++c) {
        v2f t0 = ld2(c, R0 - 4), t1 = ld2(c, R0 - 3), t2 = ld2(c, R0 - 2);
        v2f t3 = ld2(c, R0 - 1), t4 = ld2(c, R0),     t5 = ld2(c, R0 + 1);
        v2f vA = w0 * (t0 + t4) + w1 * (t1 + t3) + w2 * t2;  // vb row R0-2
        v2f vB = w0 * (t1 + t5) + w1 * (t2 + t4) + w2 * t3;  // vb row R0-1
        blm[c] = hb2(vA);
        bl0[c] = hb2(vB);
        xa[c] = t2; xbw[c] = t3; xcw[c] = t4; xdw[c] = t5;
        xnext[c] = ld2(c, R0 + 2);
    }

    auto nms_store = [&](int row) {
        float m0l = shfl1(mg0.y, lane - 1), m0r = shfl1(mg0.x, lane + 1);
        float m1l = shfl1(mg1.y, lane - 1), m1r = shfl1(mg1.x, lane + 1);
        float m2l = shfl1(mg2.y, lane - 1), m2r = shfl1(mg2.x, lane + 1);
        // element .x (col c0): left neighbor = m*l, right = own .y
        float n1x = (d1x == 0) ? mg0.x : (d1x == 1) ? m0l
                  : (d1x == 2) ? m1l   : mg0.y;
        float n2x = (d1x == 0) ? mg2.x : (d1x == 1) ? mg2.y
                  : (d1x == 2) ? mg1.y : m2l;
        // element .y (col c0+1): left = own .x, right = m*r
        float n1y = (d1y == 0) ? mg0.y : (d1y == 1) ? mg0.x
                  : (d1y == 2) ? mg1.x : m0r;
        float n2y = (d1y == 0) ? mg2.y : (d1y == 1) ? m2r
                  : (d1y == 2) ? m1r   : mg2.x;
        float sx = (mg1.x >= n1x && mg1.x >= n2x) ? mg1.x : 0.f;
        float sy = (mg1.y >= n1y && mg1.y >= n2y) ? mg1.y : 0.f;
        float vx = (sx >= t) ? sx : 1e-9f;
        float vy = (sy >= t) ? sy : 1e-9f;
        v2f o;
        o.x = __builtin_amdgcn_rcpf(1.f + __expf(-vx));
        o.y = __builtin_amdgcn_rcpf(1.f + __expf(-vy));
        bool doit = (lane >= 4 && lane < 60);
        if (CE) doit = doit && colok;
        if (doit)
            *(v2f*)&out[((size_t)b * HDIM + row) * WDIM + c0] = o;
    };

    // ---- main loop: step m computes mag[m], outputs row m-2 ----
    for (int m = R0 - 1; m <= R0 + SH; ++m) {
        v2f xn[3];
        #pragma unroll
        for (int c = 0; c < 3; ++c) xn[c] = xnext[c];
        if (m < R0 + SH) {                 // prefetch row m+4 for next iter
            #pragma unroll
            for (int c = 0; c < 3; ++c) xnext[c] = ld2(c, m + 4);
        }

        if (m >= R0 + 2) nms_store(m - 2);

        v2f best = {-1.f, -1.f}, bgx = {0.f, 0.f}, bgy = {0.f, 0.f};
        #pragma unroll
        for (int c = 0; c < 3; ++c) {
            v2f vb = w0 * (xa[c] + xn[c]) + w1 * (xbw[c] + xdw[c])
                   + w2 * xcw[c];                   // vb row m+1
            v2f blp = hb2(vb);                      // bl row m+1
            v2f bm = blm[c], bp = blp;
            if (RE) {                               // row edge-replicate
                if (m == 0)        bm = bl0[c];
                if (m == HDIM - 1) bp = bl0[c];
            }
            v2f tt = bm + 2.f * bl0[c] + bp;        // column sums
            v2f uu = bp - bm;
            float tly = shfl1(tt.y, lane - 1), trx = shfl1(tt.x, lane + 1);
            float uly = shfl1(uu.y, lane - 1), urx = shfl1(uu.x, lane + 1);
            if (CE) {                               // col edge-replicate
                if (c0 == 0)            { tly = tt.x; uly = uu.x; }
                if (c0 + 1 == WDIM - 1) { trx = tt.y; urx = uu.y; }
            }
            v2f gA = {tt.y, trx}, gB = {tly, tt.x};
            v2f gxv = 0.125f * (gA - gB);
            v2f hA = {uly, uu.x}, hB = {uu.y, urx};
            v2f gyv = 0.125f * (hA + 2.f * uu + hB);
            v2f m2v = gxv * gxv + gyv * gyv;
            if (m2v.x > best.x) { best.x = m2v.x; bgx.x = gxv.x; bgy.x = gyv.x; }
            if (m2v.y > best.y) { best.y = m2v.y; bgx.y = gxv.y; bgy.y = gyv.y; }
            blm[c] = bl0[c]; bl0[c] = blp;
            xa[c] = xbw[c]; xbw[c] = xcw[c]; xcw[c] = xdw[c]; xdw[c] = xn[c];
        }
        v2f mag2;
        mag2.x = __builtin_amdgcn_sqrtf(best.x + 1e-9f);
        mag2.y = __builtin_amdgcn_sqrtf(best.y + 1e-9f);
        if (RE && (unsigned)m >= (unsigned)HDIM) { mag2.x = 0.f; mag2.y = 0.f; }
        if (CE && !colok)                        { mag2.x = 0.f; mag2.y = 0.f; }
        const int dnx = dirof(bgx.x, bgy.x);
        const int dny = dirof(bgx.y, bgy.y);
        mg0 = mg1; mg1 = mg2; mg2 = mag2;
        d1x = d2x; d1y = d2y; d2x = dnx; d2y = dny;
    }
    nms_store(R0 + SH - 1);   // last output row
}

__global__ __launch_bounds__(256, 5) void canny_pk(
    const float* __restrict__ x, const int* __restrict__ lt,
    float* __restrict__ out)
{
    const int lane = threadIdx.x & 63;
    const int wid  = blockIdx.x * 4 + (threadIdx.x >> 6);
    const int b    = wid / (NGRP * NSTR);
    const int rem  = wid - b * (NGRP * NSTR);
    const int g    = rem >> 6;        // NSTR = 64
    const int s    = rem & (NSTR - 1);
    const int R0   = s * SH;
    const int c0   = g * GW + 2 * lane - 8;   // pair base col (even)
    const float t  = (float)lt[0];
    const float* xb0 = x + (size_t)(b * 3) * (HDIM * WDIM);

    const bool re = (s == 0) || (s == NSTR - 1);
    const bool ce = (g == 0) || (g == NGRP - 1);
    if (!re && !ce)      run<false, false>(xb0, t, out, b, R0, c0, lane);
    else if (!re)        run<false, true >(xb0, t, out, b, R0, c0, lane);
    else if (!ce)        run<true,  false>(xb0, t, out, b, R0, c0, lane);
    else                 run<true,  true >(xb0, t, out, b, R0, c0, lane);
}

extern "C" void kernel_launch(void* const* d_in, const int* in_sizes, int n_in,
                              void* d_out, int out_size, void* d_ws, size_t ws_size,
                              hipStream_t stream) {
    const float* x  = (const float*)d_in[0];
    const int*   lt = (const int*)d_in[1];
    float* out = (float*)d_out;
    // 16 b x 5 groups x 64 strips = 5120 waves = 1280 blocks
    const int nblocks = (16 * NGRP * NSTR) / 4;
    canny_pk<<<nblocks, dim3(256), 0, stream>>>(x, lt, out);
}

// Round 7
// 111.306 us; speedup vs baseline: 1.0570x; 1.0518x over previous
//
#include <hip/hip_runtime.h>
#include <math.h>

// Canny, round 6 (resubmit after infra failure): wave-rolling stencil,
// 2 cols/lane packed fp32, SH=8, software-pipelined hb stage (bl computed
// 1 row ahead of consumption), depth-2 row prefetch, scalarized
// wave-uniform addressing. B=16, C=3, H=W=512 fixed. No LDS, no barriers.

typedef float v2f __attribute__((ext_vector_type(2)));

#define HDIM 512
#define WDIM 512
#define PLANE (HDIM * WDIM)
#define SH   8
#define NSTR (HDIM / SH)   // 64 strips
#define NGRP 5             // 5 x 112 = 560 >= 512
#define GW   112

__device__ __forceinline__ float shfl1(float v, int src) {
    return __shfl(v, src, 64);
}

template<bool RE, bool CE>
__device__ __forceinline__ void run(
    const float* __restrict__ xb0, float t, float* __restrict__ out,
    int b, int R0, int c0, int lane)
{
    const bool colok = !CE || ((unsigned)c0 < (unsigned)WDIM);

    const float w0 = 0.05448868454964294f;   // gauss5(sigma=1)/sum
    const float w1 = 0.24420134200323332f;
    const float w2 = 0.4026199468942475f;
    const float T1c = 0.41421356237309503f;  // tan(pi/8)
    const float T3c = 2.414213562373095f;    // tan(3pi/8)

    auto ld2 = [&](int c, int ri) -> v2f {
        if ((CE && !colok) || (RE && (unsigned)ri >= (unsigned)HDIM)) {
            v2f z = {0.f, 0.f};
            return z;
        }
        return *(const v2f*)(xb0 + c * PLANE + ri * WDIM + c0);
    };
    // horizontal 5-tap blur on a column pair (packed)
    auto hb2 = [&](v2f v) -> v2f {
        v2f L, R;
        L.x = shfl1(v.x, lane - 1); L.y = shfl1(v.y, lane - 1);
        R.x = shfl1(v.x, lane + 1); R.y = shfl1(v.y, lane + 1);
        v2f p = {L.y, v.x};
        v2f q = {v.y, R.x};
        return w0 * (L + R) + w1 * (p + q) + w2 * v;
    };
    auto dirof = [&](float gx, float gy) -> int {
        const float gys = (gy == 0.f) ? 1e-9f : gy;
        const float sg  = (gys > 0.f) ? 1.f : -1.f;
        const float gxs = gx * sg;            // a>=c  <=>  gxs >= c*|gys|
        const float gya = fabsf(gys);
        const float a3 = T3c * gya, a1 = T1c * gya;
        return (gxs >= a3 || gxs < -a3) ? 2
             : (gxs >= a1) ? 1
             : (gxs >= -a1) ? 0 : 3;
    };

    // rolling state (at top of iteration m):
    v2f xw0[3], xw1[3], xw2[3], xw3[3];  // x rows m .. m+3
    v2f xn1[3], xn2[3];                  // prefetched x rows m+4, m+5
    v2f blA[3], blB[3], blC[3];          // bl rows m-1, m, m+1 (resolved!)
    v2f mg0 = {0.f, 0.f}, mg1 = {0.f, 0.f}, mg2 = {0.f, 0.f};
    int d1x = 0, d1y = 0, d2x = 0, d2y = 0;

    // ---- prologue (m = R0-1): bl rows R0-2..R0; x window R0-1..R0+2 ----
    #pragma unroll
    for (int c = 0; c < 3; ++c) {
        v2f t0 = ld2(c, R0 - 4), t1 = ld2(c, R0 - 3), t2 = ld2(c, R0 - 2);
        v2f t3 = ld2(c, R0 - 1), t4 = ld2(c, R0),     t5 = ld2(c, R0 + 1);
        v2f t6 = ld2(c, R0 + 2);
        v2f vA = w0 * (t0 + t4) + w1 * (t1 + t3) + w2 * t2;  // vb(R0-2)
        v2f vB = w0 * (t1 + t5) + w1 * (t2 + t4) + w2 * t3;  // vb(R0-1)
        v2f vC = w0 * (t2 + t6) + w1 * (t3 + t5) + w2 * t4;  // vb(R0)
        blA[c] = hb2(vA);
        blB[c] = hb2(vB);
        blC[c] = hb2(vC);
        xw0[c] = t3; xw1[c] = t4; xw2[c] = t5; xw3[c] = t6;
        xn1[c] = ld2(c, R0 + 3);
        xn2[c] = ld2(c, R0 + 4);
    }

    auto nms_store = [&](int row) {
        float m0l = shfl1(mg0.y, lane - 1), m0r = shfl1(mg0.x, lane + 1);
        float m1l = shfl1(mg1.y, lane - 1), m1r = shfl1(mg1.x, lane + 1);
        float m2l = shfl1(mg2.y, lane - 1), m2r = shfl1(mg2.x, lane + 1);
        // element .x (col c0): left neighbor = m*l, right = own .y
        float n1x = (d1x == 0) ? mg0.x : (d1x == 1) ? m0l
                  : (d1x == 2) ? m1l   : mg0.y;
        float n2x = (d1x == 0) ? mg2.x : (d1x == 1) ? mg2.y
                  : (d1x == 2) ? mg1.y : m2l;
        // element .y (col c0+1): left = own .x, right = m*r
        float n1y = (d1y == 0) ? mg0.y : (d1y == 1) ? mg0.x
                  : (d1y == 2) ? mg1.x : m0r;
        float n2y = (d1y == 0) ? mg2.y : (d1y == 1) ? m2r
                  : (d1y == 2) ? m1r   : mg2.x;
        float sx = (mg1.x >= n1x && mg1.x >= n2x) ? mg1.x : 0.f;
        float sy = (mg1.y >= n1y && mg1.y >= n2y) ? mg1.y : 0.f;
        float vx = (sx >= t) ? sx : 1e-9f;
        float vy = (sy >= t) ? sy : 1e-9f;
        v2f o;
        o.x = __builtin_amdgcn_rcpf(1.f + __expf(-vx));
        o.y = __builtin_amdgcn_rcpf(1.f + __expf(-vy));
        bool doit = (lane >= 4 && lane < 60);
        if (CE) doit = doit && colok;
        if (doit)
            *(v2f*)&out[((size_t)b * HDIM + row) * WDIM + c0] = o;
    };

    // ---- main loop: iter m -> sobel/mag row m (from resolved bl),
    //      pipeline bl(m+2), prefetch x(m+6), store output row m-2 ----
    for (int m = R0 - 1; m <= R0 + SH; ++m) {
        // prefetch ring: consume row m+4, issue row m+6
        v2f xn[3];
        #pragma unroll
        for (int c = 0; c < 3; ++c) {
            xn[c]  = xn1[c];
            xn1[c] = xn2[c];
            xn2[c] = ld2(c, m + 6);
        }

        if (m >= R0 + 2) nms_store(m - 2);

        // sobel row m from blA/blB/blC (all resolved last iteration)
        v2f best = {-1.f, -1.f}, bgx = {0.f, 0.f}, bgy = {0.f, 0.f};
        #pragma unroll
        for (int c = 0; c < 3; ++c) {
            v2f bm = blA[c], b0 = blB[c], bp = blC[c];
            if (RE) {                              // row edge-replicate
                if (m == 0)        bm = b0;
                if (m == HDIM - 1) bp = b0;
            }
            v2f tt = bm + 2.f * b0 + bp;           // column sums
            v2f uu = bp - bm;
            float tly = shfl1(tt.y, lane - 1), trx = shfl1(tt.x, lane + 1);
            float uly = shfl1(uu.y, lane - 1), urx = shfl1(uu.x, lane + 1);
            if (CE) {                              // col edge-replicate
                if (c0 == 0)            { tly = tt.x; uly = uu.x; }
                if (c0 + 1 == WDIM - 1) { trx = tt.y; urx = uu.y; }
            }
            v2f gA = {tt.y, trx}, gB = {tly, tt.x};
            v2f gxv = 0.125f * (gA - gB);
            v2f hA = {uly, uu.x}, hB = {uu.y, urx};
            v2f gyv = 0.125f * (hA + 2.f * uu + hB);
            v2f m2v = gxv * gxv + gyv * gyv;
            if (m2v.x > best.x) { best.x = m2v.x; bgx.x = gxv.x; bgy.x = gyv.x; }
            if (m2v.y > best.y) { best.y = m2v.y; bgx.y = gxv.y; bgy.y = gyv.y; }
        }

        // pipeline stage: vb(m+2) -> bl(m+2); shfls resolved next iter
        #pragma unroll
        for (int c = 0; c < 3; ++c) {
            v2f vb2 = w0 * (xw0[c] + xn[c]) + w1 * (xw1[c] + xw3[c])
                    + w2 * xw2[c];
            v2f blD = hb2(vb2);
            blA[c] = blB[c]; blB[c] = blC[c]; blC[c] = blD;
            xw0[c] = xw1[c]; xw1[c] = xw2[c]; xw2[c] = xw3[c]; xw3[c] = xn[c];
        }

        v2f mag2;
        mag2.x = __builtin_amdgcn_sqrtf(best.x + 1e-9f);
        mag2.y = __builtin_amdgcn_sqrtf(best.y + 1e-9f);
        if (RE && (unsigned)m >= (unsigned)HDIM) { mag2.x = 0.f; mag2.y = 0.f; }
        if (CE && !colok)                        { mag2.x = 0.f; mag2.y = 0.f; }
        const int dnx = dirof(bgx.x, bgy.x);
        const int dny = dirof(bgx.y, bgy.y);
        mg0 = mg1; mg1 = mg2; mg2 = mag2;
        d1x = d2x; d1y = d2y; d2x = dnx; d2y = dny;
    }
    nms_store(R0 + SH - 1);   // last output row
}

__global__ __launch_bounds__(256) void canny_pipe(
    const float* __restrict__ x, const int* __restrict__ lt,
    float* __restrict__ out)
{
    const int lane = threadIdx.x & 63;
    // wave-uniform -> force scalar so b/g/s/R0 and bases live in SGPRs
    const int wid  = __builtin_amdgcn_readfirstlane(
                         blockIdx.x * 4 + (threadIdx.x >> 6));
    const int b    = wid / (NGRP * NSTR);
    const int rem  = wid - b * (NGRP * NSTR);
    const int g    = rem >> 6;        // NSTR = 64
    const int s    = rem & (NSTR - 1);
    const int R0   = s * SH;
    const int c0   = g * GW + 2 * lane - 8;   // pair base col (even)
    const float t  = (float)lt[0];
    const float* xb0 = x + (size_t)(b * 3) * PLANE;

    const bool re = (s == 0) || (s == NSTR - 1);
    const bool ce = (g == 0) || (g == NGRP - 1);
    if (!re && !ce)      run<false, false>(xb0, t, out, b, R0, c0, lane);
    else if (!re)        run<false, true >(xb0, t, out, b, R0, c0, lane);
    else if (!ce)        run<true,  false>(xb0, t, out, b, R0, c0, lane);
    else                 run<true,  true >(xb0, t, out, b, R0, c0, lane);
}

extern "C" void kernel_launch(void* const* d_in, const int* in_sizes, int n_in,
                              void* d_out, int out_size, void* d_ws, size_t ws_size,
                              hipStream_t stream) {
    const float* x  = (const float*)d_in[0];
    const int*   lt = (const int*)d_in[1];
    float* out = (float*)d_out;
    // 16 b x 5 groups x 64 strips = 5120 waves = 1280 blocks
    const int nblocks = (16 * NGRP * NSTR) / 4;
    canny_pipe<<<nblocks, dim3(256), 0, stream>>>(x, lt, out);
}

// Round 9
// 110.238 us; speedup vs baseline: 1.0673x; 1.0097x over previous
//
#include <hip/hip_runtime.h>
#include <math.h>

// Canny, round 8 (resubmit after infra failure): fully software-pipelined
// wave-rolling stencil. ALL cross-lane ops (hb, sobel tt/uu, NMS neighbors)
// are issued one iteration before consumption, so lgkmcnt waits are already
// satisfied. 2 cols/lane packed fp32, SH=8, depth-2 row prefetch, scalar
// addressing. B=16, C=3, H=W=512 fixed. No LDS arrays, no barriers.

typedef float v2f __attribute__((ext_vector_type(2)));

#define HDIM 512
#define WDIM 512
#define PLANE (HDIM * WDIM)
#define SH   8
#define NSTR (HDIM / SH)   // 64 strips
#define NGRP 5             // 5 x 112 = 560 >= 512
#define GW   112

__device__ __forceinline__ float shfl1(float v, int src) {
    return __shfl(v, src, 64);
}

template<bool RE, bool CE>
__device__ __forceinline__ void run(
    const float* __restrict__ xb0, float t, float* __restrict__ out,
    int b, int R0, int c0, int lane)
{
    const bool colok = !CE || ((unsigned)c0 < (unsigned)WDIM);

    const float w0 = 0.05448868454964294f;   // gauss5(sigma=1)/sum
    const float w1 = 0.24420134200323332f;
    const float w2 = 0.4026199468942475f;
    const float T1c = 0.41421356237309503f;  // tan(pi/8)
    const float T3c = 2.414213562373095f;    // tan(3pi/8)

    auto ld2 = [&](int c, int ri) -> v2f {
        if ((CE && !colok) || (RE && (unsigned)ri >= (unsigned)HDIM)) {
            v2f z = {0.f, 0.f};
            return z;
        }
        return *(const v2f*)(xb0 + c * PLANE + ri * WDIM + c0);
    };
    // immediate horizontal blur (prologue only)
    auto hb2 = [&](v2f v) -> v2f {
        v2f L, R;
        L.x = shfl1(v.x, lane - 1); L.y = shfl1(v.y, lane - 1);
        R.x = shfl1(v.x, lane + 1); R.y = shfl1(v.y, lane + 1);
        v2f p = {L.y, v.x};
        v2f q = {v.y, R.x};
        return w0 * (L + R) + w1 * (p + q) + w2 * v;
    };
    auto dirof = [&](float gx, float gy) -> int {
        const float gys = (gy == 0.f) ? 1e-9f : gy;
        const float sg  = (gys > 0.f) ? 1.f : -1.f;
        const float gxs = gx * sg;            // a>=c  <=>  gxs >= c*|gys|
        const float gya = fabsf(gys);
        const float a3 = T3c * gya, a1 = T1c * gya;
        return (gxs >= a3 || gxs < -a3) ? 2
             : (gxs >= a1) ? 1
             : (gxs >= -a1) ? 0 : 3;
    };

    // ---- rolling state at top of iteration m ----
    v2f xw0[3], xw1[3], xw2[3], xw3[3];   // x rows m+1..m+4
    v2f xn1[3], xn2[3];                   // x rows m+5, m+6 (in flight)
    v2f vbO[3];                           // vb(m+2) own value
    float vbLx[3], vbLy[3], vbRx[3], vbRy[3];   // its shfls (ready)
    v2f blB[3], blC[3];                   // bl rows m, m+1
    v2f ttO[3], uuO[3];                   // sobel col-sums for row m
    float ttL[3], ttR[3], uuL[3], uuR[3]; // their shfls (ready)
    v2f mg0 = {0.f, 0.f}, mg1 = {0.f, 0.f}, mg2 = {0.f, 0.f}; // mag m-3..m-1
    float s0l = 0.f, s0r = 0.f, s1l = 0.f, s1r = 0.f, s2l = 0.f, s2r = 0.f;
    int d1x = 0, d1y = 0, d2x = 0, d2y = 0;  // dir rows m-2, m-1

    // ---- prologue: establish state for m = R0-1 ----
    #pragma unroll
    for (int c = 0; c < 3; ++c) {
        v2f p0 = ld2(c, R0 - 4), p1 = ld2(c, R0 - 3), p2 = ld2(c, R0 - 2);
        v2f p3 = ld2(c, R0 - 1), p4 = ld2(c, R0),     p5 = ld2(c, R0 + 1);
        v2f p6 = ld2(c, R0 + 2), p7 = ld2(c, R0 + 3);
        v2f vA = w0 * (p0 + p4) + w1 * (p1 + p3) + w2 * p2;  // vb(R0-2)
        v2f vB = w0 * (p1 + p5) + w1 * (p2 + p4) + w2 * p3;  // vb(R0-1)
        v2f vC = w0 * (p2 + p6) + w1 * (p3 + p5) + w2 * p4;  // vb(R0)
        v2f vD = w0 * (p3 + p7) + w1 * (p4 + p6) + w2 * p5;  // vb(R0+1)
        v2f blA = hb2(vA);          // bl(R0-2), prologue-only
        blB[c] = hb2(vB);           // bl(R0-1)
        blC[c] = hb2(vC);           // bl(R0)
        vbO[c] = vD;                // vb(R0+1): issue shfls, combine at m=R0-1
        vbLx[c] = shfl1(vD.x, lane - 1); vbLy[c] = shfl1(vD.y, lane - 1);
        vbRx[c] = shfl1(vD.x, lane + 1); vbRy[c] = shfl1(vD.y, lane + 1);
        xw0[c] = p4; xw1[c] = p5; xw2[c] = p6; xw3[c] = p7;
        xn1[c] = ld2(c, R0 + 4);
        xn2[c] = ld2(c, R0 + 5);
        // tt/uu for sobel row R0-1 (row -1 of s=0 strips is masked later)
        v2f bm = blA, b0 = blB[c], bp = blC[c];
        ttO[c] = bm + 2.f * b0 + bp;
        uuO[c] = bp - bm;
        ttL[c] = shfl1(ttO[c].y, lane - 1); ttR[c] = shfl1(ttO[c].x, lane + 1);
        uuL[c] = shfl1(uuO[c].y, lane - 1); uuR[c] = shfl1(uuO[c].x, lane + 1);
    }

    auto nms_store = [&](int row) {
        // element .x (col c0): left neighbor = s*l, right = own .y
        float n1x = (d1x == 0) ? mg0.x : (d1x == 1) ? s0l
                  : (d1x == 2) ? s1l   : mg0.y;
        float n2x = (d1x == 0) ? mg2.x : (d1x == 1) ? mg2.y
                  : (d1x == 2) ? mg1.y : s2l;
        // element .y (col c0+1): left = own .x, right = s*r
        float n1y = (d1y == 0) ? mg0.y : (d1y == 1) ? mg0.x
                  : (d1y == 2) ? mg1.x : s0r;
        float n2y = (d1y == 0) ? mg2.y : (d1y == 1) ? s2r
                  : (d1y == 2) ? s1r   : mg2.x;
        float sx = (mg1.x >= n1x && mg1.x >= n2x) ? mg1.x : 0.f;
        float sy = (mg1.y >= n1y && mg1.y >= n2y) ? mg1.y : 0.f;
        float vx = (sx >= t) ? sx : 1e-9f;
        float vy = (sy >= t) ? sy : 1e-9f;
        v2f o;
        o.x = __builtin_amdgcn_rcpf(1.f + __expf(-vx));
        o.y = __builtin_amdgcn_rcpf(1.f + __expf(-vy));
        bool doit = (lane >= 4 && lane < 60);
        if (CE) doit = doit && colok;
        if (doit)
            *(v2f*)&out[((size_t)b * HDIM + row) * WDIM + c0] = o;
    };

    // ---- main loop (trip count SH+2 = 10, constant) ----
    #pragma unroll 2
    for (int m = R0 - 1; m <= R0 + SH; ++m) {
        // a: prefetch ring — consume x(m+5), issue x(m+7)
        v2f xn[3], blD[3];
        #pragma unroll
        for (int c = 0; c < 3; ++c) {
            xn[c]  = xn1[c];
            xn1[c] = xn2[c];
            xn2[c] = ld2(c, m + 7);
        }

        // b: store row m-2 (all shfl inputs ready since last iteration)
        if (m >= R0 + 2) nms_store(m - 2);

        // c: combine bl(m+2) from vb(m+2) own + ready shfls
        #pragma unroll
        for (int c = 0; c < 3; ++c) {
            v2f L = {vbLx[c], vbLy[c]}, Rr = {vbRx[c], vbRy[c]};
            v2f p = {L.y, vbO[c].x};
            v2f q = {vbO[c].y, Rr.x};
            blD[c] = w0 * (L + Rr) + w1 * (p + q) + w2 * vbO[c];
        }

        // d: sobel row m from ready tt/uu + shfls
        v2f best = {-1.f, -1.f}, bgx = {0.f, 0.f}, bgy = {0.f, 0.f};
        #pragma unroll
        for (int c = 0; c < 3; ++c) {
            float tly = ttL[c], trx = ttR[c], uly = uuL[c], urx = uuR[c];
            if (CE) {                              // col edge-replicate
                if (c0 == 0)            { tly = ttO[c].x; uly = uuO[c].x; }
                if (c0 + 1 == WDIM - 1) { trx = ttO[c].y; urx = uuO[c].y; }
            }
            v2f gA = {ttO[c].y, trx}, gB = {tly, ttO[c].x};
            v2f gxv = 0.125f * (gA - gB);
            v2f hA = {uly, uuO[c].x}, hB = {uuO[c].y, urx};
            v2f gyv = 0.125f * (hA + 2.f * uuO[c] + hB);
            v2f m2v = gxv * gxv + gyv * gyv;
            if (m2v.x > best.x) { best.x = m2v.x; bgx.x = gxv.x; bgy.x = gyv.x; }
            if (m2v.y > best.y) { best.y = m2v.y; bgx.y = gxv.y; bgy.y = gyv.y; }
        }
        v2f mag2v;
        mag2v.x = __builtin_amdgcn_sqrtf(best.x + 1e-9f);
        mag2v.y = __builtin_amdgcn_sqrtf(best.y + 1e-9f);
        if (RE && (unsigned)m >= (unsigned)HDIM) { mag2v.x = 0.f; mag2v.y = 0.f; }
        if (CE && !colok)                        { mag2v.x = 0.f; mag2v.y = 0.f; }
        const int dnx = dirof(bgx.x, bgy.x);
        const int dny = dirof(bgx.y, bgy.y);

        // e: build tt/uu for row m+1, issue their shfls (consumed next iter)
        #pragma unroll
        for (int c = 0; c < 3; ++c) {
            v2f bm = blB[c], b0 = blC[c], bp = blD[c];
            if (RE) {                              // row edge-replicate
                if (m + 1 == 0)        bm = b0;
                if (m + 1 == HDIM - 1) bp = b0;
            }
            ttO[c] = bm + 2.f * b0 + bp;
            uuO[c] = bp - bm;
            ttL[c] = shfl1(ttO[c].y, lane - 1); ttR[c] = shfl1(ttO[c].x, lane + 1);
            uuL[c] = shfl1(uuO[c].y, lane - 1); uuR[c] = shfl1(uuO[c].x, lane + 1);
        }

        // f: build vb(m+3), issue its shfls; roll x window
        #pragma unroll
        for (int c = 0; c < 3; ++c) {
            v2f vbN = w0 * (xw0[c] + xn[c]) + w1 * (xw1[c] + xw3[c])
                    + w2 * xw2[c];
            vbO[c] = vbN;
            vbLx[c] = shfl1(vbN.x, lane - 1); vbLy[c] = shfl1(vbN.y, lane - 1);
            vbRx[c] = shfl1(vbN.x, lane + 1); vbRy[c] = shfl1(vbN.y, lane + 1);
            xw0[c] = xw1[c]; xw1[c] = xw2[c]; xw2[c] = xw3[c]; xw3[c] = xn[c];
        }

        // g: issue NMS shfls for next store (row m-1)
        s0l = shfl1(mg1.y, lane - 1);   s0r = shfl1(mg1.x, lane + 1);
        s1l = shfl1(mg2.y, lane - 1);   s1r = shfl1(mg2.x, lane + 1);
        s2l = shfl1(mag2v.y, lane - 1); s2r = shfl1(mag2v.x, lane + 1);

        // h: rolls (register renames under unroll)
        blB[0] = blC[0]; blC[0] = blD[0];
        blB[1] = blC[1]; blC[1] = blD[1];
        blB[2] = blC[2]; blC[2] = blD[2];
        mg0 = mg1; mg1 = mg2; mg2 = mag2v;
        d1x = d2x; d1y = d2y; d2x = dnx; d2y = dny;
    }
    nms_store(R0 + SH - 1);   // last output row
}

__global__ __launch_bounds__(256) void canny_fp(
    const float* __restrict__ x, const int* __restrict__ lt,
    float* __restrict__ out)
{
    const int lane = threadIdx.x & 63;
    // wave-uniform -> scalar registers for bases
    const int wid  = __builtin_amdgcn_readfirstlane(
                         blockIdx.x * 4 + (threadIdx.x >> 6));
    const int b    = wid / (NGRP * NSTR);
    const int rem  = wid - b * (NGRP * NSTR);
    const int g    = rem >> 6;        // NSTR = 64
    const int s    = rem & (NSTR - 1);
    const int R0   = s * SH;
    const int c0   = g * GW + 2 * lane - 8;   // pair base col (even)
    const float t  = (float)lt[0];
    const float* xb0 = x + (size_t)(b * 3) * PLANE;

    const bool re = (s == 0) || (s == NSTR - 1);
    const bool ce = (g == 0) || (g == NGRP - 1);
    if (!re && !ce)      run<false, false>(xb0, t, out, b, R0, c0, lane);
    else if (!re)        run<false, true >(xb0, t, out, b, R0, c0, lane);
    else if (!ce)        run<true,  false>(xb0, t, out, b, R0, c0, lane);
    else                 run<true,  true >(xb0, t, out, b, R0, c0, lane);
}

extern "C" void kernel_launch(void* const* d_in, const int* in_sizes, int n_in,
                              void* d_out, int out_size, void* d_ws, size_t ws_size,
                              hipStream_t stream) {
    const float* x  = (const float*)d_in[0];
    const int*   lt = (const int*)d_in[1];
    float* out = (float*)d_out;
    // 16 b x 5 groups x 64 strips = 5120 waves = 1280 blocks
    const int nblocks = (16 * NGRP * NSTR) / 4;
    canny_fp<<<nblocks, dim3(256), 0, stream>>>(x, lt, out);
}